// Round 12
// baseline (355.190 us; speedup 1.0000x reference)
//
#include <hip/hip_runtime.h>

typedef unsigned short ushort_t;
typedef __attribute__((ext_vector_type(8))) short short8;
typedef __attribute__((ext_vector_type(4))) float f32x4;
typedef __attribute__((ext_vector_type(4))) int int4v;

#define RNUM 8
#define FDIM 128

__device__ __forceinline__ float bf2f(ushort_t u) {
    union { unsigned int i; float f; } x;
    x.i = ((unsigned int)u) << 16;
    return x.f;
}
__device__ __forceinline__ ushort_t f2bf(float f) {
    union { float f; unsigned int i; } x;
    x.f = f;
    unsigned int u = x.i;
    u += 0x7fffu + ((u >> 16) & 1u);   // round-to-nearest-even
    return (ushort_t)(u >> 16);
}

// ---------------- multi-head linked-list segment index ----------------
// Round-7 form (measured best): 4 sub-lists per segment keyed by edge_id&3,
// ONE independent atomicExch per edge (round-9's atomicAdd+atomicExch
// dependent chain was latency-serialized: 65us, VALUBusy 0.5%).
// meta[i] = (src[i], prev edge in same (seg,k) list). One 8B load per hop.

__global__ void link_kernel(const int* __restrict__ src, const int* __restrict__ dst,
                            const int* __restrict__ et,
                            int* head, int2* __restrict__ meta, int E) {
    int i = blockIdx.x * 256 + threadIdx.x;
    if (i < E) {
        int seg = dst[i] * RNUM + et[i];
        int prev = atomicExch(&head[seg * 4 + (i & 3)], i);
        meta[i] = make_int2(src[i], prev);
    }
}

// ---------------- fused prologue: independent prep jobs in ONE launch --------------
// blocks 0..17: weight transpose+cast  Wt[l][r][h][f] = bf16(W_l[r][f][h])
// block  18   : copy rel_emb tail of the output
// blocks 19..19+nbHead-1: head[] = -1
// rest        : cast x (f32) -> compact bf16 xc (pad rows zeroed)
// Measured: fusion worth ~11us vs serial launches (round 11 vs round 7).

__global__ __launch_bounds__(256) void prologue_fused(
    const float* __restrict__ rel_w0, const float* __restrict__ root_w0,
    const float* __restrict__ rel_w1, const float* __restrict__ root_w1,
    ushort_t* __restrict__ Wt,
    const float* __restrict__ x, ushort_t* __restrict__ xc,
    int total, int totalPad,
    int* __restrict__ head, int nhead,
    const float* __restrict__ emb, float* __restrict__ outEmb, int nemb,
    int nbHead) {
    __shared__ ushort_t t[128 * 130];
    int b = blockIdx.x, tid = threadIdx.x;
    if (b < 18) {
        int layer = (b >= 9) ? 1 : 0;
        int r = b - layer * 9;         // 0..8, r=8 -> root
        const float* rel  = layer ? rel_w1 : rel_w0;
        const float* root = layer ? root_w1 : root_w0;
        const float* src = (r < 8) ? (rel + r * 16384) : root;
        for (int idx = tid; idx < 16384; idx += 256)
            t[(idx >> 7) * 130 + (idx & 127)] = f2bf(src[idx]);
        __syncthreads();
        ushort_t* d = Wt + (layer * 9 + r) * 16384;
        for (int idx = tid; idx < 16384; idx += 256)
            d[idx] = t[(idx & 127) * 130 + (idx >> 7)];
    } else if (b == 18) {
        for (int i = tid; i < nemb; i += 256) outEmb[i] = emb[i];
    } else if (b < 19 + nbHead) {
        int i = (b - 19) * 256 + tid;
        if (i < nhead) head[i] = -1;
    } else {
        int i = ((b - 19 - nbHead) * 256 + tid) * 8;
        if (i < totalPad) {
            ushort_t o[8];
            if (i < total) {
                float4 v0 = *(const float4*)(x + i);
                float4 v1 = *(const float4*)(x + i + 4);
                o[0] = f2bf(v0.x); o[1] = f2bf(v0.y); o[2] = f2bf(v0.z); o[3] = f2bf(v0.w);
                o[4] = f2bf(v1.x); o[5] = f2bf(v1.y); o[6] = f2bf(v1.z); o[7] = f2bf(v1.w);
            } else {
#pragma unroll
                for (int k = 0; k < 8; ++k) o[k] = 0;
            }
            *(int4v*)(xc + i) = *(int4v*)o;
        }
    }
}

// ---------------- phase A: per-(node,rel) segment means ----------------
// ROUND-7 VERSION VERBATIM (measured 61.2-62.7us; at the random-gather
// pattern roofline ~3.8-4.1 TB/s across VALUBusy 31-64% configs; round-9's
// VALU-cut falsification proved duration is pinned by gather service rate).

__global__ __launch_bounds__(256) void seg_mean(const int4v* __restrict__ head4,
                                                const int2* __restrict__ meta,
                                                const ushort_t* __restrict__ X,   // [NPAD][128]
                                                ushort_t* __restrict__ Mm,        // [NPAD][8][128]
                                                int NSEG) {
    int t = blockIdx.x * 256 + threadIdx.x;
    int seg = t >> 4;
    int l16 = t & 15;
    if (seg >= NSEG) return;
    const ushort_t* gbase = X + l16 * 8;

    float acc[8];
#pragma unroll
    for (int k = 0; k < 8; ++k) acc[k] = 0.f;

    int4v h4 = head4[seg];           // 4 sub-chain heads in one 16B load
    int j[4], s[4], n[4];
#pragma unroll
    for (int c = 0; c < 4; ++c) j[c] = h4[c];
#pragma unroll
    for (int c = 0; c < 4; ++c)
        if (j[c] >= 0) { int2 m = meta[j[c]]; s[c] = m.x; n[c] = m.y; }

    int cnt = 0;
    // loop while ANY sub-chain active (AND of ids has sign bit set iff all -1)
    while ((j[0] & j[1] & j[2] & j[3]) >= 0) {
        int4v v[4];
#pragma unroll
        for (int c = 0; c < 4; ++c)
            if (j[c] >= 0) v[c] = *(const int4v*)(gbase + ((size_t)s[c] << 7));
        int2 m2[4];
#pragma unroll
        for (int c = 0; c < 4; ++c)
            if (j[c] >= 0 && n[c] >= 0) m2[c] = meta[n[c]];
#pragma unroll
        for (int c = 0; c < 4; ++c) {
            if (j[c] >= 0) {
                const ushort_t* p = (const ushort_t*)&v[c];
#pragma unroll
                for (int k = 0; k < 8; ++k) acc[k] += bf2f(p[k]);
                ++cnt;
                j[c] = n[c];
                s[c] = m2[c].x;
                n[c] = m2[c].y;
            }
        }
    }

    float sc = (cnt > 0) ? 1.0f / (float)cnt : 0.f;
    ushort_t ov[8];
#pragma unroll
    for (int k = 0; k < 8; ++k) ov[k] = f2bf(acc[k] * sc);
    *(int4v*)(Mm + ((size_t)seg << 7) + l16 * 8) = *(int4v*)ov;
}

// ---------------- phase B: dense GEMM  C[128n x 128h] = [Mm | Xc] @ Wt^T ----------------
// SYMMETRIC 2-DEEP register pipeline with RAW barriers. Why: __syncthreads
// emits an unconditional s_waitcnt vmcnt(0) before s_barrier, which drained
// any register prefetch at each slot boundary (round-10 failure, mechanism
// confirmed). Raw __builtin_amdgcn_s_barrier() + explicit lgkmcnt(0) after
// ds_writes lets the compiler emit COUNTED vmcnt waits from dataflow: slot
// r+2's 8 loads (issued at iteration r) stay in flight across the barrier
// and the writeLds of slot r+1 (waits vmcnt(8)). Load->stage distance is a
// full iteration (~900cy) >= HBM latency. r-loop fully unrolled so all set
// selection is static (runtime-indexed vector arrays would hit scratch).
// Sync structure per iteration: compute(r) -> barrier(all reads done) ->
// ds_write slot r+1 -> lgkmcnt(0) -> barrier(writes visible) -> next.

template <bool FINAL>
__global__ __launch_bounds__(512, 4) void rgcn_gemm(
    const ushort_t* __restrict__ Mm,   // [NPAD][8*128]
    const ushort_t* __restrict__ Xc,   // [NPAD][128]  (slot 8 / root input)
    const ushort_t* __restrict__ Wt,   // [9][128][128]
    const float* __restrict__ bias, float* __restrict__ outF,
    ushort_t* __restrict__ Xout, int N) {
    __shared__ ushort_t As[128 * 128];
    __shared__ ushort_t Bs[128 * 128];
    int tid = threadIdx.x;
    int wv = tid >> 6, lane = tid & 63;
    int l16 = lane & 15, q = lane >> 4;
    int nodeBase = blockIdx.x * 128;

    f32x4 acc[8];
#pragma unroll
    for (int ct = 0; ct < 8; ++ct) acc[ct] = (f32x4){0.f, 0.f, 0.f, 0.f};

    int rowv[4], cv[4];
#pragma unroll
    for (int i = 0; i < 4; ++i) {
        int L = i * 512 + tid;
        rowv[i] = L >> 4;               // 0..127
        cv[i]   = (L & 15) ^ (rowv[i] & 15);  // swizzled chunk
    }

    int4v aS0[4], bS0[4], aS1[4], bS1[4];   // two named sets (static indexing)

#define LOADSET(AR, BR, R)                                                         \
    {                                                                              \
        _Pragma("unroll")                                                          \
        for (int i = 0; i < 4; ++i) {                                              \
            const ushort_t* ga = ((R) < 8)                                         \
                ? Mm + ((size_t)(nodeBase + rowv[i]) << 10) + (R) * 128 + cv[i] * 8\
                : Xc + ((size_t)(nodeBase + rowv[i]) << 7) + cv[i] * 8;            \
            AR[i] = *(const int4v*)ga;                                             \
            BR[i] = *(const int4v*)(Wt + (R) * 16384 + rowv[i] * 128 + cv[i] * 8); \
        }                                                                          \
    }

#define WRITESET(AR, BR)                                                           \
    {                                                                              \
        _Pragma("unroll")                                                          \
        for (int i = 0; i < 4; ++i) {                                              \
            int L = i * 512 + tid;                                                 \
            *(int4v*)((char*)As + (size_t)L * 16) = AR[i];                         \
            *(int4v*)((char*)Bs + (size_t)L * 16) = BR[i];                         \
        }                                                                          \
    }

    // prologue: slot0 -> set0, slot1 -> set1 (stays in flight); stage slot0
    LOADSET(aS0, bS0, 0)
    LOADSET(aS1, bS1, 1)
    WRITESET(aS0, bS0)                 // compiler waits only set0 (counted vmcnt)
    asm volatile("s_waitcnt lgkmcnt(0)" ::: "memory");
    __builtin_amdgcn_s_barrier();

#pragma unroll
    for (int r = 0; r < 9; ++r) {
        // slot r in LDS; slot r+1 in set ((r+1)&1); free set (r&1) takes slot r+2
        if (r < 7) {
            if ((r & 1) == 0) { LOADSET(aS0, bS0, r + 2) }
            else              { LOADSET(aS1, bS1, r + 2) }
        }
#pragma unroll
        for (int s = 0; s < 4; ++s) {
            int pos = ((s * 4 + q) ^ l16) * 16;
            short8 a = *(const short8*)((const char*)As + (wv * 16 + l16) * 256 + pos);
#pragma unroll
            for (int ct = 0; ct < 8; ++ct) {
                short8 b = *(const short8*)((const char*)Bs + (ct * 16 + l16) * 256 + pos);
                acc[ct] = __builtin_amdgcn_mfma_f32_16x16x32_bf16(a, b, acc[ct], 0, 0, 0);
            }
        }
        __builtin_amdgcn_s_barrier();       // all waves done reading slot r
        if (r < 8) {
            // stage slot r+1 (loads issued a full iteration ago -> latency covered;
            // compiler emits vmcnt(8) here, leaving slot r+2's loads in flight)
            if ((r & 1) == 0) { WRITESET(aS1, bS1) }
            else              { WRITESET(aS0, bS0) }
            asm volatile("s_waitcnt lgkmcnt(0)" ::: "memory");
            __builtin_amdgcn_s_barrier();    // writes visible before next compute
        }
    }
#undef LOADSET
#undef WRITESET

    // epilogue: C layout col = lane&15, row = q*4 + reg (within wave's 16-row tile)
#pragma unroll
    for (int ct = 0; ct < 8; ++ct) {
        int h = ct * 16 + l16;
        float bv = bias[h];
#pragma unroll
        for (int reg = 0; reg < 4; ++reg) {
            int node = nodeBase + wv * 16 + q * 4 + reg;
            float v = acc[ct][reg] + bv;
            if (FINAL) {
                if (node < N) outF[(size_t)node * FDIM + h] = v;
            } else {
                // pad rows written as 0 (keeps h1c defined; acc there is garbage)
                Xout[(size_t)node * FDIM + h] =
                    (node < N) ? f2bf(fmaxf(v, 0.f)) : (ushort_t)0;
            }
        }
    }
}

// ---------------- launch ----------------

extern "C" void kernel_launch(void* const* d_in, const int* in_sizes, int n_in,
                              void* d_out, int out_size, void* d_ws, size_t ws_size,
                              hipStream_t stream) {
    const float* x        = (const float*)d_in[0];
    const int* edge_index = (const int*)d_in[1];
    const int* edge_type  = (const int*)d_in[2];
    const float* rel_w0   = (const float*)d_in[3];
    const float* root_w0  = (const float*)d_in[4];
    const float* bias0    = (const float*)d_in[5];
    const float* rel_w1   = (const float*)d_in[6];
    const float* root_w1  = (const float*)d_in[7];
    const float* bias1    = (const float*)d_in[8];
    const float* rel_emb  = (const float*)d_in[9];

    int N = in_sizes[0] / FDIM;   // 50000
    int E = in_sizes[1] / 2;      // 800000
    int NSEG = N * RNUM;          // 400000
    const int* src = edge_index;
    const int* dst = edge_index + E;

    int nb_gemm = (N + 127) / 128;      // 391
    int NPAD = nb_gemm * 128;           // 50048

    char* w = (char*)d_ws;
    auto alloc = [&](size_t bytes) -> char* {
        char* p = w;
        w += (bytes + 255) & ~(size_t)255;
        return p;
    };
    int* head     = (int*)alloc((size_t)NSEG * 4 * 4);          // 4 sub-lists per segment
    int2* meta    = (int2*)alloc((size_t)E * 8);
    ushort_t* Wt  = (ushort_t*)alloc((size_t)2 * 9 * 16384 * 2);
    ushort_t* xc  = (ushort_t*)alloc((size_t)NPAD * FDIM * 2);        // 12.8 MB
    ushort_t* h1c = (ushort_t*)alloc((size_t)NPAD * FDIM * 2);        // 12.8 MB
    ushort_t* Mm  = (ushort_t*)alloc((size_t)NPAD * RNUM * FDIM * 2); // ~102.5 MB
    (void)ws_size; (void)n_in; (void)out_size;

    int nhead   = NSEG * 4;
    int nb_head = (nhead + 255) / 256;
    int nb_E    = (E + 255) / 256;
    int nb_mean = (NSEG * 16) / 256;                 // 25000
    int nb_cast = (NPAD * FDIM) / (256 * 8);         // 3128
    int nb_pro  = 19 + nb_head + nb_cast;

    prologue_fused<<<nb_pro, 256, 0, stream>>>(
        rel_w0, root_w0, rel_w1, root_w1, Wt,
        x, xc, N * FDIM, NPAD * FDIM,
        head, nhead,
        rel_emb, (float*)d_out + (size_t)N * FDIM, in_sizes[9],
        nb_head);
    link_kernel<<<nb_E, 256, 0, stream>>>(src, dst, edge_type, head, meta, E);

    seg_mean<<<nb_mean, 256, 0, stream>>>((const int4v*)head, meta, xc, Mm, NSEG);
    rgcn_gemm<false><<<nb_gemm, 512, 0, stream>>>(Mm, xc, Wt, bias0, nullptr, h1c, N);
    seg_mean<<<nb_mean, 256, 0, stream>>>((const int4v*)head, meta, h1c, Mm, NSEG);
    rgcn_gemm<true><<<nb_gemm, 512, 0, stream>>>(Mm, h1c, Wt + 9 * 16384, bias1,
                                                 (float*)d_out, nullptr, N);
}

// Round 13
// 321.457 us; speedup vs baseline: 1.1049x; 1.1049x over previous
//
#include <hip/hip_runtime.h>

typedef unsigned short ushort_t;
typedef __attribute__((ext_vector_type(8))) short short8;
typedef __attribute__((ext_vector_type(4))) float f32x4;
typedef __attribute__((ext_vector_type(4))) int int4v;

#define RNUM 8
#define FDIM 128

__device__ __forceinline__ float bf2f(ushort_t u) {
    union { unsigned int i; float f; } x;
    x.i = ((unsigned int)u) << 16;
    return x.f;
}
__device__ __forceinline__ ushort_t f2bf(float f) {
    union { float f; unsigned int i; } x;
    x.f = f;
    unsigned int u = x.i;
    u += 0x7fffu + ((u >> 16) & 1u);   // round-to-nearest-even
    return (ushort_t)(u >> 16);
}

// ---------------- multi-head linked-list segment index ----------------
// Round-7 form (measured best): 4 sub-lists per segment keyed by edge_id&3,
// ONE independent atomicExch per edge (round-9's atomicAdd+atomicExch
// dependent chain was latency-serialized: 65us, VALUBusy 0.5%).
// meta[i] = (src[i], prev edge in same (seg,k) list). One 8B load per hop.

__global__ void link_kernel(const int* __restrict__ src, const int* __restrict__ dst,
                            const int* __restrict__ et,
                            int* head, int2* __restrict__ meta, int E) {
    int i = blockIdx.x * 256 + threadIdx.x;
    if (i < E) {
        int seg = dst[i] * RNUM + et[i];
        int prev = atomicExch(&head[seg * 4 + (i & 3)], i);
        meta[i] = make_int2(src[i], prev);
    }
}

// ---------------- fused prologue: independent prep jobs in ONE launch --------------
// blocks 0..17: weight transpose+cast  Wt[l][r][h][f] = bf16(W_l[r][f][h])
// block  18   : copy rel_emb tail of the output
// blocks 19..19+nbHead-1: head[] = -1
// rest        : cast x (f32) -> compact bf16 xc (pad rows zeroed)
// Measured: fusion worth ~11us vs serial launches (round 11 vs round 7).

__global__ __launch_bounds__(256) void prologue_fused(
    const float* __restrict__ rel_w0, const float* __restrict__ root_w0,
    const float* __restrict__ rel_w1, const float* __restrict__ root_w1,
    ushort_t* __restrict__ Wt,
    const float* __restrict__ x, ushort_t* __restrict__ xc,
    int total, int totalPad,
    int* __restrict__ head, int nhead,
    const float* __restrict__ emb, float* __restrict__ outEmb, int nemb,
    int nbHead) {
    __shared__ ushort_t t[128 * 130];
    int b = blockIdx.x, tid = threadIdx.x;
    if (b < 18) {
        int layer = (b >= 9) ? 1 : 0;
        int r = b - layer * 9;         // 0..8, r=8 -> root
        const float* rel  = layer ? rel_w1 : rel_w0;
        const float* root = layer ? root_w1 : root_w0;
        const float* src = (r < 8) ? (rel + r * 16384) : root;
        for (int idx = tid; idx < 16384; idx += 256)
            t[(idx >> 7) * 130 + (idx & 127)] = f2bf(src[idx]);
        __syncthreads();
        ushort_t* d = Wt + (layer * 9 + r) * 16384;
        for (int idx = tid; idx < 16384; idx += 256)
            d[idx] = t[(idx & 127) * 130 + (idx >> 7)];
    } else if (b == 18) {
        for (int i = tid; i < nemb; i += 256) outEmb[i] = emb[i];
    } else if (b < 19 + nbHead) {
        int i = (b - 19) * 256 + tid;
        if (i < nhead) head[i] = -1;
    } else {
        int i = ((b - 19 - nbHead) * 256 + tid) * 8;
        if (i < totalPad) {
            ushort_t o[8];
            if (i < total) {
                float4 v0 = *(const float4*)(x + i);
                float4 v1 = *(const float4*)(x + i + 4);
                o[0] = f2bf(v0.x); o[1] = f2bf(v0.y); o[2] = f2bf(v0.z); o[3] = f2bf(v0.w);
                o[4] = f2bf(v1.x); o[5] = f2bf(v1.y); o[6] = f2bf(v1.z); o[7] = f2bf(v1.w);
            } else {
#pragma unroll
                for (int k = 0; k < 8; ++k) o[k] = 0;
            }
            *(int4v*)(xc + i) = *(int4v*)o;
        }
    }
}

// ---------------- phase A: per-(node,rel) segment means ----------------
// ROUND-7 VERSION VERBATIM (measured 61.2-62.7us; at the random-gather
// pattern roofline ~3.8-4.1 TB/s across VALUBusy 31-64% configs; round-9's
// VALU-cut falsification proved duration is pinned by gather service rate).

__global__ __launch_bounds__(256) void seg_mean(const int4v* __restrict__ head4,
                                                const int2* __restrict__ meta,
                                                const ushort_t* __restrict__ X,   // [NPAD][128]
                                                ushort_t* __restrict__ Mm,        // [NPAD][8][128]
                                                int NSEG) {
    int t = blockIdx.x * 256 + threadIdx.x;
    int seg = t >> 4;
    int l16 = t & 15;
    if (seg >= NSEG) return;
    const ushort_t* gbase = X + l16 * 8;

    float acc[8];
#pragma unroll
    for (int k = 0; k < 8; ++k) acc[k] = 0.f;

    int4v h4 = head4[seg];           // 4 sub-chain heads in one 16B load
    int j[4], s[4], n[4];
#pragma unroll
    for (int c = 0; c < 4; ++c) j[c] = h4[c];
#pragma unroll
    for (int c = 0; c < 4; ++c)
        if (j[c] >= 0) { int2 m = meta[j[c]]; s[c] = m.x; n[c] = m.y; }

    int cnt = 0;
    // loop while ANY sub-chain active (AND of ids has sign bit set iff all -1)
    while ((j[0] & j[1] & j[2] & j[3]) >= 0) {
        int4v v[4];
#pragma unroll
        for (int c = 0; c < 4; ++c)
            if (j[c] >= 0) v[c] = *(const int4v*)(gbase + ((size_t)s[c] << 7));
        int2 m2[4];
#pragma unroll
        for (int c = 0; c < 4; ++c)
            if (j[c] >= 0 && n[c] >= 0) m2[c] = meta[n[c]];
#pragma unroll
        for (int c = 0; c < 4; ++c) {
            if (j[c] >= 0) {
                const ushort_t* p = (const ushort_t*)&v[c];
#pragma unroll
                for (int k = 0; k < 8; ++k) acc[k] += bf2f(p[k]);
                ++cnt;
                j[c] = n[c];
                s[c] = m2[c].x;
                n[c] = m2[c].y;
            }
        }
    }

    float sc = (cnt > 0) ? 1.0f / (float)cnt : 0.f;
    ushort_t ov[8];
#pragma unroll
    for (int k = 0; k < 8; ++k) ov[k] = f2bf(acc[k] * sc);
    *(int4v*)(Mm + ((size_t)seg << 7) + l16 * 8) = *(int4v*)ov;
}

// ---------------- phase B: dense GEMM  C[128n x 128h] = [Mm | Xc] @ Wt^T ----------------
// Symmetric 2-deep register pipeline with raw barriers (round-12 structure,
// functionally verified). ROUND-13 FIX: __launch_bounds__(512, 2).
// Round-12 evidence: with (512,4) the allocator targeted 8 waves/EU and
// capped VGPR at 64 -- the two 32-VGPR staging sets spilled to scratch
// (WRITE_SIZE 86.7MB vs 13-26MB real output, occupancy 21%, MfmaUtil 8%).
// The kernel is LDS-limited to 2 blocks/CU (16 waves/CU = 4 waves/EU)
// REGARDLESS of VGPR use, so capping at 64 bought nothing. (512,2) raises
// the cap to 256: both sets stay resident, same occupancy, no scratch.
// Sync per iteration: compute(r) -> barrier -> ds_write slot r+1 (counted
// vmcnt from dataflow; slot r+2's loads stay in flight) -> lgkmcnt(0) ->
// barrier -> next. Load->stage distance ~1 iteration >= HBM latency.

template <bool FINAL>
__global__ __launch_bounds__(512, 2) void rgcn_gemm(
    const ushort_t* __restrict__ Mm,   // [NPAD][8*128]
    const ushort_t* __restrict__ Xc,   // [NPAD][128]  (slot 8 / root input)
    const ushort_t* __restrict__ Wt,   // [9][128][128]
    const float* __restrict__ bias, float* __restrict__ outF,
    ushort_t* __restrict__ Xout, int N) {
    __shared__ ushort_t As[128 * 128];
    __shared__ ushort_t Bs[128 * 128];
    int tid = threadIdx.x;
    int wv = tid >> 6, lane = tid & 63;
    int l16 = lane & 15, q = lane >> 4;
    int nodeBase = blockIdx.x * 128;

    f32x4 acc[8];
#pragma unroll
    for (int ct = 0; ct < 8; ++ct) acc[ct] = (f32x4){0.f, 0.f, 0.f, 0.f};

    int rowv[4], cv[4];
#pragma unroll
    for (int i = 0; i < 4; ++i) {
        int L = i * 512 + tid;
        rowv[i] = L >> 4;               // 0..127
        cv[i]   = (L & 15) ^ (rowv[i] & 15);  // swizzled chunk
    }

    int4v aS0[4], bS0[4], aS1[4], bS1[4];   // two named sets (static indexing)

#define LOADSET(AR, BR, R)                                                         \
    {                                                                              \
        _Pragma("unroll")                                                          \
        for (int i = 0; i < 4; ++i) {                                              \
            const ushort_t* ga = ((R) < 8)                                         \
                ? Mm + ((size_t)(nodeBase + rowv[i]) << 10) + (R) * 128 + cv[i] * 8\
                : Xc + ((size_t)(nodeBase + rowv[i]) << 7) + cv[i] * 8;            \
            AR[i] = *(const int4v*)ga;                                             \
            BR[i] = *(const int4v*)(Wt + (R) * 16384 + rowv[i] * 128 + cv[i] * 8); \
        }                                                                          \
    }

#define WRITESET(AR, BR)                                                           \
    {                                                                              \
        _Pragma("unroll")                                                          \
        for (int i = 0; i < 4; ++i) {                                              \
            int L = i * 512 + tid;                                                 \
            *(int4v*)((char*)As + (size_t)L * 16) = AR[i];                         \
            *(int4v*)((char*)Bs + (size_t)L * 16) = BR[i];                         \
        }                                                                          \
    }

    // prologue: slot0 -> set0, slot1 -> set1 (stays in flight); stage slot0
    LOADSET(aS0, bS0, 0)
    LOADSET(aS1, bS1, 1)
    WRITESET(aS0, bS0)                 // compiler waits only set0 (counted vmcnt)
    asm volatile("s_waitcnt lgkmcnt(0)" ::: "memory");
    __builtin_amdgcn_s_barrier();

#pragma unroll
    for (int r = 0; r < 9; ++r) {
        // slot r in LDS; slot r+1 in set ((r+1)&1); free set (r&1) takes slot r+2
        if (r < 7) {
            if ((r & 1) == 0) { LOADSET(aS0, bS0, r + 2) }
            else              { LOADSET(aS1, bS1, r + 2) }
        }
#pragma unroll
        for (int s = 0; s < 4; ++s) {
            int pos = ((s * 4 + q) ^ l16) * 16;
            short8 a = *(const short8*)((const char*)As + (wv * 16 + l16) * 256 + pos);
#pragma unroll
            for (int ct = 0; ct < 8; ++ct) {
                short8 b = *(const short8*)((const char*)Bs + (ct * 16 + l16) * 256 + pos);
                acc[ct] = __builtin_amdgcn_mfma_f32_16x16x32_bf16(a, b, acc[ct], 0, 0, 0);
            }
        }
        __builtin_amdgcn_s_barrier();       // all waves done reading slot r
        if (r < 8) {
            // stage slot r+1 (loads issued a full iteration ago -> latency covered;
            // compiler emits counted vmcnt here, leaving slot r+2's loads in flight)
            if ((r & 1) == 0) { WRITESET(aS1, bS1) }
            else              { WRITESET(aS0, bS0) }
            asm volatile("s_waitcnt lgkmcnt(0)" ::: "memory");
            __builtin_amdgcn_s_barrier();    // writes visible before next compute
        }
    }
#undef LOADSET
#undef WRITESET

    // epilogue: C layout col = lane&15, row = q*4 + reg (within wave's 16-row tile)
#pragma unroll
    for (int ct = 0; ct < 8; ++ct) {
        int h = ct * 16 + l16;
        float bv = bias[h];
#pragma unroll
        for (int reg = 0; reg < 4; ++reg) {
            int node = nodeBase + wv * 16 + q * 4 + reg;
            float v = acc[ct][reg] + bv;
            if (FINAL) {
                if (node < N) outF[(size_t)node * FDIM + h] = v;
            } else {
                // pad rows written as 0 (keeps h1c defined; acc there is garbage)
                Xout[(size_t)node * FDIM + h] =
                    (node < N) ? f2bf(fmaxf(v, 0.f)) : (ushort_t)0;
            }
        }
    }
}

// ---------------- launch ----------------

extern "C" void kernel_launch(void* const* d_in, const int* in_sizes, int n_in,
                              void* d_out, int out_size, void* d_ws, size_t ws_size,
                              hipStream_t stream) {
    const float* x        = (const float*)d_in[0];
    const int* edge_index = (const int*)d_in[1];
    const int* edge_type  = (const int*)d_in[2];
    const float* rel_w0   = (const float*)d_in[3];
    const float* root_w0  = (const float*)d_in[4];
    const float* bias0    = (const float*)d_in[5];
    const float* rel_w1   = (const float*)d_in[6];
    const float* root_w1  = (const float*)d_in[7];
    const float* bias1    = (const float*)d_in[8];
    const float* rel_emb  = (const float*)d_in[9];

    int N = in_sizes[0] / FDIM;   // 50000
    int E = in_sizes[1] / 2;      // 800000
    int NSEG = N * RNUM;          // 400000
    const int* src = edge_index;
    const int* dst = edge_index + E;

    int nb_gemm = (N + 127) / 128;      // 391
    int NPAD = nb_gemm * 128;           // 50048

    char* w = (char*)d_ws;
    auto alloc = [&](size_t bytes) -> char* {
        char* p = w;
        w += (bytes + 255) & ~(size_t)255;
        return p;
    };
    int* head     = (int*)alloc((size_t)NSEG * 4 * 4);          // 4 sub-lists per segment
    int2* meta    = (int2*)alloc((size_t)E * 8);
    ushort_t* Wt  = (ushort_t*)alloc((size_t)2 * 9 * 16384 * 2);
    ushort_t* xc  = (ushort_t*)alloc((size_t)NPAD * FDIM * 2);        // 12.8 MB
    ushort_t* h1c = (ushort_t*)alloc((size_t)NPAD * FDIM * 2);        // 12.8 MB
    ushort_t* Mm  = (ushort_t*)alloc((size_t)NPAD * RNUM * FDIM * 2); // ~102.5 MB
    (void)ws_size; (void)n_in; (void)out_size;

    int nhead   = NSEG * 4;
    int nb_head = (nhead + 255) / 256;
    int nb_E    = (E + 255) / 256;
    int nb_mean = (NSEG * 16) / 256;                 // 25000
    int nb_cast = (NPAD * FDIM) / (256 * 8);         // 3128
    int nb_pro  = 19 + nb_head + nb_cast;

    prologue_fused<<<nb_pro, 256, 0, stream>>>(
        rel_w0, root_w0, rel_w1, root_w1, Wt,
        x, xc, N * FDIM, NPAD * FDIM,
        head, nhead,
        rel_emb, (float*)d_out + (size_t)N * FDIM, in_sizes[9],
        nb_head);
    link_kernel<<<nb_E, 256, 0, stream>>>(src, dst, edge_type, head, meta, E);

    seg_mean<<<nb_mean, 256, 0, stream>>>((const int4v*)head, meta, xc, Mm, NSEG);
    rgcn_gemm<false><<<nb_gemm, 512, 0, stream>>>(Mm, xc, Wt, bias0, nullptr, h1c, N);
    seg_mean<<<nb_mean, 256, 0, stream>>>((const int4v*)head, meta, h1c, Mm, NSEG);
    rgcn_gemm<true><<<nb_gemm, 512, 0, stream>>>(Mm, h1c, Wt + 9 * 16384, bias1,
                                                 (float*)d_out, nullptr, N);
}

// Round 14
// 305.561 us; speedup vs baseline: 1.1624x; 1.0520x over previous
//
#include <hip/hip_runtime.h>

typedef unsigned short ushort_t;
typedef __attribute__((ext_vector_type(8))) short short8;
typedef __attribute__((ext_vector_type(4))) float f32x4;
typedef __attribute__((ext_vector_type(4))) int int4v;

#define RNUM 8
#define FDIM 128

__device__ __forceinline__ float bf2f(ushort_t u) {
    union { unsigned int i; float f; } x;
    x.i = ((unsigned int)u) << 16;
    return x.f;
}
__device__ __forceinline__ ushort_t f2bf(float f) {
    union { float f; unsigned int i; } x;
    x.f = f;
    unsigned int u = x.i;
    u += 0x7fffu + ((u >> 16) & 1u);   // round-to-nearest-even
    return (ushort_t)(u >> 16);
}

// ---------------- multi-head linked-list segment index ----------------
// Round-7 form (measured best): 4 sub-lists per segment keyed by edge_id&3,
// ONE independent atomicExch per edge (round-9's atomicAdd+atomicExch
// dependent chain was latency-serialized: 65us, VALUBusy 0.5%).
// meta[i] = (src[i], prev edge in same (seg,k) list). One 8B load per hop.

__global__ void link_kernel(const int* __restrict__ src, const int* __restrict__ dst,
                            const int* __restrict__ et,
                            int* head, int2* __restrict__ meta, int E) {
    int i = blockIdx.x * 256 + threadIdx.x;
    if (i < E) {
        int seg = dst[i] * RNUM + et[i];
        int prev = atomicExch(&head[seg * 4 + (i & 3)], i);
        meta[i] = make_int2(src[i], prev);
    }
}

// ---------------- fused prologue: independent prep jobs in ONE launch --------------
// blocks 0..17: weight transpose+cast  Wt[l][r][h][f] = bf16(W_l[r][f][h])
// block  18   : copy rel_emb tail of the output
// blocks 19..19+nbHead-1: head[] = -1
// rest        : cast x (f32) -> compact bf16 xc (pad rows zeroed)
// Measured: fusion worth ~11us vs serial launches (round 11 vs round 7).

__global__ __launch_bounds__(256) void prologue_fused(
    const float* __restrict__ rel_w0, const float* __restrict__ root_w0,
    const float* __restrict__ rel_w1, const float* __restrict__ root_w1,
    ushort_t* __restrict__ Wt,
    const float* __restrict__ x, ushort_t* __restrict__ xc,
    int total, int totalPad,
    int* __restrict__ head, int nhead,
    const float* __restrict__ emb, float* __restrict__ outEmb, int nemb,
    int nbHead) {
    __shared__ ushort_t t[128 * 130];
    int b = blockIdx.x, tid = threadIdx.x;
    if (b < 18) {
        int layer = (b >= 9) ? 1 : 0;
        int r = b - layer * 9;         // 0..8, r=8 -> root
        const float* rel  = layer ? rel_w1 : rel_w0;
        const float* root = layer ? root_w1 : root_w0;
        const float* src = (r < 8) ? (rel + r * 16384) : root;
        for (int idx = tid; idx < 16384; idx += 256)
            t[(idx >> 7) * 130 + (idx & 127)] = f2bf(src[idx]);
        __syncthreads();
        ushort_t* d = Wt + (layer * 9 + r) * 16384;
        for (int idx = tid; idx < 16384; idx += 256)
            d[idx] = t[(idx & 127) * 130 + (idx >> 7)];
    } else if (b == 18) {
        for (int i = tid; i < nemb; i += 256) outEmb[i] = emb[i];
    } else if (b < 19 + nbHead) {
        int i = (b - 19) * 256 + tid;
        if (i < nhead) head[i] = -1;
    } else {
        int i = ((b - 19 - nbHead) * 256 + tid) * 8;
        if (i < totalPad) {
            ushort_t o[8];
            if (i < total) {
                float4 v0 = *(const float4*)(x + i);
                float4 v1 = *(const float4*)(x + i + 4);
                o[0] = f2bf(v0.x); o[1] = f2bf(v0.y); o[2] = f2bf(v0.z); o[3] = f2bf(v0.w);
                o[4] = f2bf(v1.x); o[5] = f2bf(v1.y); o[6] = f2bf(v1.z); o[7] = f2bf(v1.w);
            } else {
#pragma unroll
                for (int k = 0; k < 8; ++k) o[k] = 0;
            }
            *(int4v*)(xc + i) = *(int4v*)o;
        }
    }
}

// ---------------- phase A: per-(node,rel) segment means ----------------
// ROUND-7 VERSION VERBATIM (measured 61.1-62.7us; at the random-gather
// pattern roofline ~3.8-4.1 TB/s across VALUBusy 31-64% configs; round-9's
// VALU-cut falsification proved duration is pinned by gather service rate).

__global__ __launch_bounds__(256) void seg_mean(const int4v* __restrict__ head4,
                                                const int2* __restrict__ meta,
                                                const ushort_t* __restrict__ X,   // [NPAD][128]
                                                ushort_t* __restrict__ Mm,        // [NPAD][8][128]
                                                int NSEG) {
    int t = blockIdx.x * 256 + threadIdx.x;
    int seg = t >> 4;
    int l16 = t & 15;
    if (seg >= NSEG) return;
    const ushort_t* gbase = X + l16 * 8;

    float acc[8];
#pragma unroll
    for (int k = 0; k < 8; ++k) acc[k] = 0.f;

    int4v h4 = head4[seg];           // 4 sub-chain heads in one 16B load
    int j[4], s[4], n[4];
#pragma unroll
    for (int c = 0; c < 4; ++c) j[c] = h4[c];
#pragma unroll
    for (int c = 0; c < 4; ++c)
        if (j[c] >= 0) { int2 m = meta[j[c]]; s[c] = m.x; n[c] = m.y; }

    int cnt = 0;
    // loop while ANY sub-chain active (AND of ids has sign bit set iff all -1)
    while ((j[0] & j[1] & j[2] & j[3]) >= 0) {
        int4v v[4];
#pragma unroll
        for (int c = 0; c < 4; ++c)
            if (j[c] >= 0) v[c] = *(const int4v*)(gbase + ((size_t)s[c] << 7));
        int2 m2[4];
#pragma unroll
        for (int c = 0; c < 4; ++c)
            if (j[c] >= 0 && n[c] >= 0) m2[c] = meta[n[c]];
#pragma unroll
        for (int c = 0; c < 4; ++c) {
            if (j[c] >= 0) {
                const ushort_t* p = (const ushort_t*)&v[c];
#pragma unroll
                for (int k = 0; k < 8; ++k) acc[k] += bf2f(p[k]);
                ++cnt;
                j[c] = n[c];
                s[c] = m2[c].x;
                n[c] = m2[c].y;
            }
        }
    }

    float sc = (cnt > 0) ? 1.0f / (float)cnt : 0.f;
    ushort_t ov[8];
#pragma unroll
    for (int k = 0; k < 8; ++k) ov[k] = f2bf(acc[k] * sc);
    *(int4v*)(Mm + ((size_t)seg << 7) + l16 * 8) = *(int4v*)ov;
}

// ---------------- phase B: dense GEMM  C[128n x 128h] = [Mm | Xc] @ Wt^T ----------------
// ROUND-11 STRUCTURE (1-deep register-staged pipeline, measured best total
// 303.8us) with ONE change: __launch_bounds__(512, 2) instead of (512, 4).
// Occupancy/VGPR matrix from rounds 11/12/13:
//   1-deep (512,4): VGPR cap 64, needs ~90 -> moderate spill, 2 blk/CU. 303.8
//   2-deep (512,4): cap 64, needs ~120 -> massive spill (WRITE 86.7MB). 355.2
//   2-deep (512,2): cap 256, ~>128 used -> 1 blk/CU (TLP halved).       321.5
// This round fills the missing cell: 1-deep at (512,2) -> ~90 VGPR: no spill
// AND <=128 so the LDS-limited 2 blocks/CU (16 waves/CU) is preserved.

template <bool FINAL>
__global__ __launch_bounds__(512, 2) void rgcn_gemm(
    const ushort_t* __restrict__ Mm,   // [NPAD][8*128]
    const ushort_t* __restrict__ Xc,   // [NPAD][128]  (slot 8 / root input)
    const ushort_t* __restrict__ Wt,   // [9][128][128]
    const float* __restrict__ bias, float* __restrict__ outF,
    ushort_t* __restrict__ Xout, int N) {
    __shared__ ushort_t As[128 * 128];
    __shared__ ushort_t Bs[128 * 128];
    int tid = threadIdx.x;
    int wv = tid >> 6, lane = tid & 63;
    int l16 = lane & 15, q = lane >> 4;
    int nodeBase = blockIdx.x * 128;

    f32x4 acc[8];
#pragma unroll
    for (int ct = 0; ct < 8; ++ct) acc[ct] = (f32x4){0.f, 0.f, 0.f, 0.f};

    int4v aReg[4], bReg[4];

    auto issueLoads = [&](int r) {
#pragma unroll
        for (int i = 0; i < 4; ++i) {
            int L = i * 512 + tid;          // 16B slot index, wave-contiguous
            int row = L >> 4;               // 0..127
            int c = (L & 15) ^ (row & 15);  // logical chunk for this slot (swizzle)
            const ushort_t* ga = (r < 8)
                ? Mm + ((size_t)(nodeBase + row) << 10) + r * 128 + c * 8
                : Xc + ((size_t)(nodeBase + row) << 7) + c * 8;
            aReg[i] = *(const int4v*)ga;
            bReg[i] = *(const int4v*)(Wt + r * 16384 + row * 128 + c * 8);
        }
    };
    auto writeLds = [&]() {
#pragma unroll
        for (int i = 0; i < 4; ++i) {
            int L = i * 512 + tid;
            *(int4v*)((char*)As + (size_t)L * 16) = aReg[i];
            *(int4v*)((char*)Bs + (size_t)L * 16) = bReg[i];
        }
    };

    issueLoads(0);
    writeLds();
    __syncthreads();

    for (int r = 0; r < 9; ++r) {
        if (r < 8) issueLoads(r + 1);       // in flight across the compute phase
#pragma unroll
        for (int s = 0; s < 4; ++s) {
            int pos = ((s * 4 + q) ^ l16) * 16;
            short8 a = *(const short8*)((const char*)As + (wv * 16 + l16) * 256 + pos);
#pragma unroll
            for (int ct = 0; ct < 8; ++ct) {
                short8 b = *(const short8*)((const char*)Bs + (ct * 16 + l16) * 256 + pos);
                acc[ct] = __builtin_amdgcn_mfma_f32_16x16x32_bf16(a, b, acc[ct], 0, 0, 0);
            }
        }
        __syncthreads();                     // all LDS reads of slot r done
        if (r < 8) {
            writeLds();                      // waits vmcnt on the staged regs only
            __syncthreads();                 // writes visible before next compute
        }
    }

    // epilogue: C layout col = lane&15, row = q*4 + reg (within wave's 16-row tile)
#pragma unroll
    for (int ct = 0; ct < 8; ++ct) {
        int h = ct * 16 + l16;
        float bv = bias[h];
#pragma unroll
        for (int reg = 0; reg < 4; ++reg) {
            int node = nodeBase + wv * 16 + q * 4 + reg;
            float v = acc[ct][reg] + bv;
            if (FINAL) {
                if (node < N) outF[(size_t)node * FDIM + h] = v;
            } else {
                // pad rows written as 0 (keeps h1c defined; acc there is garbage)
                Xout[(size_t)node * FDIM + h] =
                    (node < N) ? f2bf(fmaxf(v, 0.f)) : (ushort_t)0;
            }
        }
    }
}

// ---------------- launch ----------------

extern "C" void kernel_launch(void* const* d_in, const int* in_sizes, int n_in,
                              void* d_out, int out_size, void* d_ws, size_t ws_size,
                              hipStream_t stream) {
    const float* x        = (const float*)d_in[0];
    const int* edge_index = (const int*)d_in[1];
    const int* edge_type  = (const int*)d_in[2];
    const float* rel_w0   = (const float*)d_in[3];
    const float* root_w0  = (const float*)d_in[4];
    const float* bias0    = (const float*)d_in[5];
    const float* rel_w1   = (const float*)d_in[6];
    const float* root_w1  = (const float*)d_in[7];
    const float* bias1    = (const float*)d_in[8];
    const float* rel_emb  = (const float*)d_in[9];

    int N = in_sizes[0] / FDIM;   // 50000
    int E = in_sizes[1] / 2;      // 800000
    int NSEG = N * RNUM;          // 400000
    const int* src = edge_index;
    const int* dst = edge_index + E;

    int nb_gemm = (N + 127) / 128;      // 391
    int NPAD = nb_gemm * 128;           // 50048

    char* w = (char*)d_ws;
    auto alloc = [&](size_t bytes) -> char* {
        char* p = w;
        w += (bytes + 255) & ~(size_t)255;
        return p;
    };
    int* head     = (int*)alloc((size_t)NSEG * 4 * 4);          // 4 sub-lists per segment
    int2* meta    = (int2*)alloc((size_t)E * 8);
    ushort_t* Wt  = (ushort_t*)alloc((size_t)2 * 9 * 16384 * 2);
    ushort_t* xc  = (ushort_t*)alloc((size_t)NPAD * FDIM * 2);        // 12.8 MB
    ushort_t* h1c = (ushort_t*)alloc((size_t)NPAD * FDIM * 2);        // 12.8 MB
    ushort_t* Mm  = (ushort_t*)alloc((size_t)NPAD * RNUM * FDIM * 2); // ~102.5 MB
    (void)ws_size; (void)n_in; (void)out_size;

    int nhead   = NSEG * 4;
    int nb_head = (nhead + 255) / 256;
    int nb_E    = (E + 255) / 256;
    int nb_mean = (NSEG * 16) / 256;                 // 25000
    int nb_cast = (NPAD * FDIM) / (256 * 8);         // 3128
    int nb_pro  = 19 + nb_head + nb_cast;

    prologue_fused<<<nb_pro, 256, 0, stream>>>(
        rel_w0, root_w0, rel_w1, root_w1, Wt,
        x, xc, N * FDIM, NPAD * FDIM,
        head, nhead,
        rel_emb, (float*)d_out + (size_t)N * FDIM, in_sizes[9],
        nb_head);
    link_kernel<<<nb_E, 256, 0, stream>>>(src, dst, edge_type, head, meta, E);

    seg_mean<<<nb_mean, 256, 0, stream>>>((const int4v*)head, meta, xc, Mm, NSEG);
    rgcn_gemm<false><<<nb_gemm, 512, 0, stream>>>(Mm, xc, Wt, bias0, nullptr, h1c, N);
    seg_mean<<<nb_mean, 256, 0, stream>>>((const int4v*)head, meta, h1c, Mm, NSEG);
    rgcn_gemm<true><<<nb_gemm, 512, 0, stream>>>(Mm, h1c, Wt + 9 * 16384, bias1,
                                                 (float*)d_out, nullptr, N);
}